// Round 4
// baseline (2275.088 us; speedup 1.0000x reference)
//
#include <hip/hip_runtime.h>
#include <hip/hip_bf16.h>

#define AA 64
#define NBRF 41
#define ORIGD 92
#define NATOM 50000
#define MM 12
#define NB 1000
#define NPCC 50
#define NEDGE (NATOM*MM)
constexpr float EPS_BN = 1e-5f;

using bf16 = __hip_bfloat16;
typedef short s16x8 __attribute__((ext_vector_type(8)));
typedef float f32x4 __attribute__((ext_vector_type(4)));

__device__ __forceinline__ float u2f(unsigned short u) {
    union { float f; unsigned int i; } v; v.i = ((unsigned int)u) << 16; return v.f;
}
__device__ __forceinline__ unsigned short f2bu(float f) {
    bf16 h = __float2bfloat16(f);
    return *reinterpret_cast<unsigned short*>(&h);
}
__device__ __forceinline__ float softplusf(float x) {
    return fmaxf(x, 0.f) + log1pf(expf(-fabsf(x)));
}
__device__ __forceinline__ float sigmoidf(float x) {
    return 1.f / (1.f + expf(-x));
}

// ---------------- zero small stats region ----------------
__global__ void k_zero(float* p, int n) {
    int i = blockIdx.x * blockDim.x + threadIdx.x;
    if (i < n) p[i] = 0.f;
}

// ---------------- embed: x = atom_fea @ emb_w  (N,92)@(92,64) ----------------
__global__ __launch_bounds__(256) void k_embed(const float* __restrict__ af,
                                               const float* __restrict__ w,
                                               float* __restrict__ x) {
    __shared__ float wl[ORIGD * AA];
    __shared__ float al[4][ORIGD];
    int t = threadIdx.x;
    for (int i = t; i < ORIGD * AA; i += 256) wl[i] = w[i];
    int n0 = blockIdx.x * 4;
    for (int i = t; i < 4 * ORIGD; i += 256) {
        int a = i / ORIGD, k = i - a * ORIGD;
        al[a][k] = af[(size_t)(n0 + a) * ORIGD + k];
    }
    __syncthreads();
    int c = t & 63, a = t >> 6;
    float acc = 0.f;
    #pragma unroll 4
    for (int k = 0; k < ORIGD; ++k)
        acc += al[a][k] * wl[k * AA + c];
    x[(size_t)(n0 + a) * AA + c] = acc;
}

// ---------------- y0 = x@W[0:64], y1 = x@W[64:128] ----------------
__global__ __launch_bounds__(256) void k_y01(const float* __restrict__ x,
                                             const float* __restrict__ W, // 169x128 layer base
                                             float* __restrict__ y0, float* __restrict__ y1) {
    __shared__ float wl[64 * 128];
    __shared__ float xl[16][AA];
    int t = threadIdx.x;
    int n0 = blockIdx.x * 16;
    for (int i = t; i < 16 * AA; i += 256) {
        int a = i >> 6, k = i & 63;
        xl[a][k] = x[(size_t)(n0 + a) * AA + k];
    }
    int tc = t & 31, sub = t >> 5;
    int c0 = tc * 4;
    for (int half = 0; half < 2; ++half) {
        if (half) __syncthreads();
        const float* Wh = W + (size_t)half * 64 * 128;
        for (int i = t; i < 64 * 128; i += 256) wl[i] = Wh[i];
        __syncthreads();
        float* yout = half ? y1 : y0;
        for (int ah = 0; ah < 2; ++ah) {
            int a = sub + ah * 8;
            float a0=0,a1=0,a2=0,a3=0;
            #pragma unroll 8
            for (int k = 0; k < AA; ++k) {
                float xv = xl[a][k];
                float4 w4 = *reinterpret_cast<const float4*>(&wl[k * 128 + c0]);
                a0 += xv * w4.x; a1 += xv * w4.y; a2 += xv * w4.z; a3 += xv * w4.w;
            }
            float4 r = {a0,a1,a2,a3};
            *reinterpret_cast<float4*>(&yout[(size_t)(n0 + a) * 128 + c0]) = r;
        }
    }
}

// ================= MFMA edge-GEMM passes =================
// Per block: 16 atoms -> 192 edges. GEMM: [192 x 41] @ [41 x 128], K padded to 64.
// A (bf16): rows=edges, 72-elem row stride (144B, bank-safe). B = W2^T: rows=cols(n).
// Fragments (verified layouts): A/B lane holds idx=lane&15, k=quad*8+j; C/D col=lane&15, row=quad*4+reg.

__device__ __forceinline__ void stage_AB(int t, int n0,
                                         const float* __restrict__ nf,
                                         const float* __restrict__ W2,
                                         const float* __restrict__ y0,
                                         const int* __restrict__ nidx,
                                         unsigned short* Al, unsigned short* Bl,
                                         unsigned short* y0l, int* il) {
    const float* fg = nf + (size_t)n0 * MM * NBRF;
    for (int i = t; i < 192 * 64; i += 256) {
        int m = i >> 6, k = i & 63;
        float v = (k < NBRF) ? fg[m * NBRF + k] : 0.f;
        Al[m * 72 + k] = f2bu(v);
    }
    for (int i = t; i < 128 * 64; i += 256) {
        int k = i >> 7, n = i & 127;
        float v = (k < NBRF) ? W2[k * 128 + n] : 0.f;
        Bl[n * 72 + k] = f2bu(v);
    }
    for (int i = t; i < 16 * 128; i += 256) {
        int a = i >> 7, c = i & 127;
        y0l[i] = f2bu(y0[(size_t)(n0 + a) * 128 + c]);
    }
    for (int i = t; i < 192; i += 256) il[i] = nidx[n0 * MM + i];
}

#define MFMA_LOOP(acc, Al, Bl, w, ln, quad)                                         \
    _Pragma("unroll")                                                               \
    for (int mt = 0; mt < 3; ++mt) {                                                \
        int mrow = ((w) * 3 + mt) * 16 + (ln);                                      \
        s16x8 a0 = *reinterpret_cast<const s16x8*>(&(Al)[mrow * 72 + (quad) * 8]);  \
        s16x8 a1 = *reinterpret_cast<const s16x8*>(&(Al)[mrow * 72 + (quad) * 8 + 32]); \
        _Pragma("unroll")                                                           \
        for (int nt = 0; nt < 8; ++nt) {                                            \
            int nrow = nt * 16 + (ln);                                              \
            s16x8 b0 = *reinterpret_cast<const s16x8*>(&(Bl)[nrow * 72 + (quad) * 8]);      \
            s16x8 b1 = *reinterpret_cast<const s16x8*>(&(Bl)[nrow * 72 + (quad) * 8 + 32]); \
            acc[mt][nt] = __builtin_amdgcn_mfma_f32_16x16x32_bf16(a0, b0, acc[mt][nt], 0, 0, 0); \
            acc[mt][nt] = __builtin_amdgcn_mfma_f32_16x16x32_bf16(a1, b1, acc[mt][nt], 0, 0, 0); \
        }                                                                           \
    }

// pass A: stats (sum, sumsq per col) of gated = y0[a] + y1[g] + nf@W2
__global__ __launch_bounds__(256, 3) void k_passA(const float* __restrict__ y0,
                                                  const float* __restrict__ y1,
                                                  const float* __restrict__ nf,
                                                  const int* __restrict__ nidx,
                                                  const float* __restrict__ W2,
                                                  float* __restrict__ stats) {
    __shared__ __attribute__((aligned(16))) unsigned short Al[192 * 72]; // 27648B
    __shared__ __attribute__((aligned(16))) unsigned short Bl[128 * 72]; // 18432B
    __shared__ unsigned short y0l[16 * 128];                             // 4096B
    __shared__ int il[192];
    int t = threadIdx.x;
    int n0 = blockIdx.x * 16;
    stage_AB(t, n0, nf, W2, y0, nidx, Al, Bl, y0l, il);
    __syncthreads();

    int w = t >> 6, lane = t & 63, ln = lane & 15, quad = lane >> 4;
    f32x4 acc[3][8];
    f32x4 z4 = {0.f, 0.f, 0.f, 0.f};
    for (int i = 0; i < 3; ++i) for (int j = 0; j < 8; ++j) acc[i][j] = z4;
    MFMA_LOOP(acc, Al, Bl, w, ln, quad);
    __syncthreads(); // all waves done with Al before aliasing as red

    float s[8] = {0,0,0,0,0,0,0,0}, q[8] = {0,0,0,0,0,0,0,0};
    #pragma unroll
    for (int mt = 0; mt < 3; ++mt) {
        #pragma unroll
        for (int reg = 0; reg < 4; ++reg) {
            int m = (w * 3 + mt) * 16 + quad * 4 + reg;
            int a = m / MM;
            const float* y1r = y1 + (size_t)il[m] * 128;
            #pragma unroll
            for (int nt = 0; nt < 8; ++nt) {
                int n = nt * 16 + ln;
                float r = acc[mt][nt][reg] + u2f(y0l[a * 128 + n]) + y1r[n];
                s[nt] += r; q[nt] += r * r;
            }
        }
    }
    #pragma unroll
    for (int nt = 0; nt < 8; ++nt) {
        s[nt] += __shfl_xor(s[nt], 16); s[nt] += __shfl_xor(s[nt], 32);
        q[nt] += __shfl_xor(q[nt], 16); q[nt] += __shfl_xor(q[nt], 32);
    }
    float* red = reinterpret_cast<float*>(Al); // [4 waves][8 nt][16 ln][2]
    if (quad == 0) {
        #pragma unroll
        for (int nt = 0; nt < 8; ++nt) {
            red[((w * 8 + nt) * 16 + ln) * 2 + 0] = s[nt];
            red[((w * 8 + nt) * 16 + ln) * 2 + 1] = q[nt];
        }
    }
    __syncthreads();
    {
        int c = t >> 1, j = t & 1; // c in 0..127
        float v = 0.f;
        #pragma unroll
        for (int w2 = 0; w2 < 4; ++w2)
            v += red[((w2 * 8 + (c >> 4)) * 16 + (c & 15)) * 2 + j];
        atomicAdd(&stats[j * 128 + c], v);
    }
}

// ---------------- bn1 fold ----------------
__global__ void k_sc1(const float* __restrict__ stats, const float* __restrict__ g,
                      const float* __restrict__ b, float* __restrict__ sc) {
    int c = threadIdx.x; // 128
    float cnt = (float)NEDGE;
    float mean = stats[c] / cnt;
    float var = stats[128 + c] / cnt - mean * mean;
    float inv = rsqrtf(var + EPS_BN);
    float scale = g[c] * inv;
    sc[c] = scale;
    sc[128 + c] = b[c] - mean * scale;
}

// pass B: recompute gated, apply BN1 + sigmoid*softplus, sum over neighbors; bn2 stats
__global__ __launch_bounds__(256, 3) void k_passB(const float* __restrict__ y0,
                                                  const float* __restrict__ y1,
                                                  const float* __restrict__ nf,
                                                  const int* __restrict__ nidx,
                                                  const float* __restrict__ W2,
                                                  const float* __restrict__ sc,
                                                  float* __restrict__ summed,
                                                  float* __restrict__ stats2) {
    __shared__ __attribute__((aligned(16))) unsigned short Al[192 * 72];
    __shared__ __attribute__((aligned(16))) unsigned short Bl[128 * 72];
    __shared__ unsigned short y0l[16 * 128];
    __shared__ int il[192];
    int t = threadIdx.x;
    int n0 = blockIdx.x * 16;
    stage_AB(t, n0, nf, W2, y0, nidx, Al, Bl, y0l, il);
    __syncthreads();

    int w = t >> 6, lane = t & 63, ln = lane & 15, quad = lane >> 4;
    f32x4 acc[3][8];
    f32x4 z4 = {0.f, 0.f, 0.f, 0.f};
    for (int i = 0; i < 3; ++i) for (int j = 0; j < 8; ++j) acc[i][j] = z4;
    MFMA_LOOP(acc, Al, Bl, w, ln, quad);
    __syncthreads(); // Al dead -> alias as sum_l

    float* sum_l = reinterpret_cast<float*>(Al); // [16 atoms][64 cols]
    for (int i = t; i < 16 * 64; i += 256) sum_l[i] = 0.f;
    float scF[4], shF[4], scC[4], shC[4];
    #pragma unroll
    for (int nt = 0; nt < 4; ++nt) {
        int cc = nt * 16 + ln;
        scF[nt] = sc[cc];      shF[nt] = sc[128 + cc];
        scC[nt] = sc[64 + cc]; shC[nt] = sc[192 + cc];
    }
    __syncthreads();
    #pragma unroll
    for (int mt = 0; mt < 3; ++mt) {
        #pragma unroll
        for (int reg = 0; reg < 4; ++reg) {
            int m = (w * 3 + mt) * 16 + quad * 4 + reg;
            int a = m / MM;
            const float* y1r = y1 + (size_t)il[m] * 128;
            #pragma unroll
            for (int nt = 0; nt < 4; ++nt) {
                int cc = nt * 16 + ln;
                float rf = (acc[mt][nt][reg]     + u2f(y0l[a * 128 + cc])      + y1r[cc])      * scF[nt] + shF[nt];
                float rc = (acc[mt][nt + 4][reg] + u2f(y0l[a * 128 + 64 + cc]) + y1r[64 + cc]) * scC[nt] + shC[nt];
                atomicAdd(&sum_l[a * 64 + cc], sigmoidf(rf) * softplusf(rc));
            }
        }
    }
    __syncthreads();
    if (t < 64) {
        float sA = 0.f, qA = 0.f;
        for (int a = 0; a < 16; ++a) {
            float v = sum_l[a * 64 + t];
            summed[(size_t)(n0 + a) * AA + t] = v;
            sA += v; qA += v * v;
        }
        atomicAdd(&stats2[t], sA);
        atomicAdd(&stats2[64 + t], qA);
    }
}

// ---------------- bn2 fold ----------------
__global__ void k_sc2(const float* __restrict__ stats2, const float* __restrict__ g,
                      const float* __restrict__ b, float* __restrict__ sc2) {
    int c = threadIdx.x; // 64
    float cnt = (float)NATOM;
    float mean = stats2[c] / cnt;
    float var = stats2[64 + c] / cnt - mean * mean;
    float inv = rsqrtf(var + EPS_BN);
    float scale = g[c] * inv;
    sc2[c] = scale;
    sc2[64 + c] = b[c] - mean * scale;
}

// ---------------- x = softplus(x + bn2(summed)) ----------------
__global__ void k_update(float* __restrict__ x, const float* __restrict__ summed,
                         const float* __restrict__ sc2) {
    int i = blockIdx.x * blockDim.x + threadIdx.x;
    if (i < NATOM * AA) {
        int c = i & 63;
        float s = summed[i] * sc2[c] + sc2[64 + c];
        x[i] = softplusf(x[i] + s);
    }
}

// ---------------- bilinear head: q, fc1, log_softmax ----------------
__global__ __launch_bounds__(256) void k_q(const float* __restrict__ x, const int* __restrict__ cidx,
                                           const float* __restrict__ adjw, // 6*64*64
                                           const float* __restrict__ adjb, // 6
                                           const float* __restrict__ fc1w, // 36
                                           const float* __restrict__ fc1b, // 6
                                           float* __restrict__ logp) {
    __shared__ float Ao[64 * 64];
    __shared__ float cfl[16][64];
    __shared__ float qv[16][6];
    int t = threadIdx.x;
    int p0 = blockIdx.x * 16;
    int e = t & 63, who = t >> 6;
    for (int i = t; i < 16 * 64; i += 256) {
        int a = i >> 6, d = i & 63;
        cfl[a][d] = x[(size_t)cidx[p0 + a] * AA + d];
    }
    for (int o = 0; o < 6; ++o) {
        __syncthreads();
        for (int i = t; i < 4096; i += 256) Ao[i] = adjw[o * 4096 + i];
        __syncthreads();
        float bo = adjb[o];
        for (int aa = 0; aa < 4; ++aa) {
            int a = who * 4 + aa;
            float td = 0.f;
            #pragma unroll 8
            for (int d = 0; d < 64; ++d)
                td += cfl[a][d] * Ao[d * 64 + e];
            float v = td * cfl[a][e];
            for (int off = 32; off; off >>= 1) v += __shfl_down(v, off);
            if (e == 0) qv[a][o] = v + bo;
        }
    }
    __syncthreads();
    if (t < 16) {
        float q2[6];
        float mx = -1e30f;
        for (int o2 = 0; o2 < 6; ++o2) {
            float acc = fc1b[o2];
            for (int o = 0; o < 6; ++o) acc += qv[t][o] * fc1w[o * 6 + o2];
            q2[o2] = acc; mx = fmaxf(mx, acc);
        }
        float se = 0.f;
        for (int o2 = 0; o2 < 6; ++o2) se += expf(q2[o2] - mx);
        float lse = mx + logf(se);
        for (int o2 = 0; o2 < 6; ++o2) logp[(size_t)(p0 + t) * 6 + o2] = q2[o2] - lse;
    }
}

// ---------------- edge_prob broadcast write ----------------
__global__ void k_edge(const float* __restrict__ logp, float* __restrict__ out0) {
    int i4 = blockIdx.x * blockDim.x + threadIdx.x;
    if (i4 >= (NB * NPCC * NPCC * 6) / 4) return;
    int e = i4 * 4;
    int b = e / (NPCC * NPCC * 6);
    int rr = e - b * (NPCC * NPCC * 6);
    const float* lb = &logp[(size_t)b * NPCC * 6];
    float4 v;
    int r0 = rr % 300;       v.x = lb[r0];
    int r1 = (rr + 1) % 300; v.y = lb[r1];
    int r2 = (rr + 2) % 300; v.z = lb[r2];
    int r3 = (rr + 3) % 300; v.w = lb[r3];
    *reinterpret_cast<float4*>(&out0[e]) = v;
}

// ---------------- atom_feature = cf @ af_w + af_b ----------------
__global__ __launch_bounds__(256) void k_af(const float* __restrict__ x, const int* __restrict__ cidx,
                                            const float* __restrict__ afw,
                                            const float* __restrict__ afb,
                                            float* __restrict__ out1) {
    __shared__ float wl[AA * ORIGD];
    __shared__ float cfl[2][AA];
    int t = threadIdx.x;
    for (int i = t; i < AA * ORIGD; i += 256) wl[i] = afw[i];
    int p0 = blockIdx.x * 2;
    if (t < 128) {
        int a = t >> 6, e = t & 63;
        cfl[a][e] = x[(size_t)cidx[p0 + a] * AA + e];
    }
    __syncthreads();
    int a = t >> 7, c = t & 127;
    if (c < ORIGD) {
        float acc = afb[c];
        #pragma unroll 8
        for (int k = 0; k < AA; ++k)
            acc += cfl[a][k] * wl[k * ORIGD + c];
        out1[(size_t)(p0 + a) * ORIGD + c] = acc;
    }
}

extern "C" void kernel_launch(void* const* d_in, const int* in_sizes, int n_in,
                              void* d_out, int out_size, void* d_ws, size_t ws_size,
                              hipStream_t stream) {
    (void)in_sizes; (void)n_in; (void)out_size; (void)ws_size;
    const float* atom_fea  = (const float*)d_in[0];
    const float* nbr_fea   = (const float*)d_in[1];
    const int*   nbr_idx   = (const int*)d_in[2];
    const int*   cidx      = (const int*)d_in[3];
    const float* emb_w     = (const float*)d_in[4];
    const float* fc_full_w = (const float*)d_in[5];
    // d_in[6] fc_full_b: cancelled by batchnorm
    const float* bn1_g = (const float*)d_in[7];
    const float* bn1_b = (const float*)d_in[8];
    const float* bn2_g = (const float*)d_in[9];
    const float* bn2_b = (const float*)d_in[10];
    const float* adj_w = (const float*)d_in[11];
    const float* adj_b = (const float*)d_in[12];
    const float* fc1_w = (const float*)d_in[13];
    const float* fc1_b = (const float*)d_in[14];
    const float* af_w  = (const float*)d_in[15];
    const float* af_b  = (const float*)d_in[16];

    float* out0 = (float*)d_out;
    float* out1 = out0 + (size_t)NB * NPCC * NPCC * 6;

    float* ws = (float*)d_ws;
    float* x      = ws;
    float* y0     = x + (size_t)NATOM * AA;
    float* y1     = y0 + (size_t)NATOM * 128;
    float* summed = y1 + (size_t)NATOM * 128;
    float* logp   = summed + (size_t)NATOM * AA;
    float* stats1 = logp + (size_t)NATOM * 6;
    float* sc1    = stats1 + 256;
    float* stats2 = sc1 + 256;
    float* sc2    = stats2 + 128;

    k_embed<<<NATOM / 4, 256, 0, stream>>>(atom_fea, emb_w, x);
    for (int layer = 0; layer < 3; ++layer) {
        const float* W  = fc_full_w + (size_t)layer * 169 * 128;
        const float* W2 = W + 128 * 128;
        k_zero<<<3, 256, 0, stream>>>(stats1, 768);
        k_y01<<<NATOM / 16, 256, 0, stream>>>(x, W, y0, y1);
        k_passA<<<NATOM / 16, 256, 0, stream>>>(y0, y1, nbr_fea, nbr_idx, W2, stats1);
        k_sc1<<<1, 128, 0, stream>>>(stats1, bn1_g + layer * 128, bn1_b + layer * 128, sc1);
        k_passB<<<NATOM / 16, 256, 0, stream>>>(y0, y1, nbr_fea, nbr_idx, W2, sc1, summed, stats2);
        k_sc2<<<1, 64, 0, stream>>>(stats2, bn2_g + layer * 64, bn2_b + layer * 64, sc2);
        k_update<<<(NATOM * AA + 255) / 256, 256, 0, stream>>>(x, summed, sc2);
    }
    k_q<<<NATOM / 16, 256, 0, stream>>>(x, cidx, adj_w, adj_b, fc1_w, fc1_b, logp);
    k_edge<<<((NB * NPCC * NPCC * 6) / 4 + 255) / 256, 256, 0, stream>>>(logp, out0);
    k_af<<<NATOM / 2, 256, 0, stream>>>(x, cidx, af_w, af_b, out1);
}

// Round 5
// 1414.564 us; speedup vs baseline: 1.6083x; 1.6083x over previous
//
#include <hip/hip_runtime.h>
#include <hip/hip_bf16.h>

#define AA 64
#define NBRF 41
#define ORIGD 92
#define NATOM 50000
#define MM 12
#define NB 1000
#define NPCC 50
#define NEDGE (NATOM*MM)
constexpr float EPS_BN = 1e-5f;

using bf16 = __hip_bfloat16;
typedef short s16x8 __attribute__((ext_vector_type(8)));
typedef float f32x4 __attribute__((ext_vector_type(4)));

__device__ __forceinline__ float u2f(unsigned short u) {
    union { float f; unsigned int i; } v; v.i = ((unsigned int)u) << 16; return v.f;
}
__device__ __forceinline__ unsigned short f2bu(float f) {
    bf16 h = __float2bfloat16(f);
    return *reinterpret_cast<unsigned short*>(&h);
}
// fast transcendental versions (native v_exp_f32 / v_log_f32 / v_rcp_f32)
__device__ __forceinline__ float fsigmoid(float x) {
    float e = __expf(-x);
    return __builtin_amdgcn_rcpf(1.f + e);
}
__device__ __forceinline__ float fsoftplus(float x) {
    return fmaxf(x, 0.f) + __logf(1.f + __expf(-fabsf(x)));
}

// ---------------- zero small stats region ----------------
__global__ void k_zero(float* p, int n) {
    int i = blockIdx.x * blockDim.x + threadIdx.x;
    if (i < n) p[i] = 0.f;
}

// ---------------- prep: nbr_fea -> bf16, K padded 41->64 ----------------
__global__ __launch_bounds__(256) void k_prepA(const float* __restrict__ nf,
                                               unsigned short* __restrict__ nfb) {
    size_t i = (size_t)blockIdx.x * 256 + threadIdx.x; // over NEDGE*64
    int e = (int)(i >> 6), k = (int)(i & 63);
    float v = (k < NBRF) ? nf[(size_t)e * NBRF + k] : 0.f;
    nfb[i] = f2bu(v);
}

// ---------------- prep: W2^T -> bf16 [128 rows(n)][72 (k, padded)] ----------------
__global__ void k_prepB(const float* __restrict__ W2, unsigned short* __restrict__ Bt) {
    for (int i = threadIdx.x; i < 128 * 72; i += 256) {
        int n = i / 72, kk = i - n * 72;
        float v = (kk < NBRF) ? W2[kk * 128 + n] : 0.f;
        Bt[i] = f2bu(v);
    }
}

// ---------------- embed: x = atom_fea @ emb_w  (N,92)@(92,64) ----------------
__global__ __launch_bounds__(256) void k_embed(const float* __restrict__ af,
                                               const float* __restrict__ w,
                                               float* __restrict__ x) {
    __shared__ float wl[ORIGD * AA];
    __shared__ float al[4][ORIGD];
    int t = threadIdx.x;
    for (int i = t; i < ORIGD * AA; i += 256) wl[i] = w[i];
    int n0 = blockIdx.x * 4;
    for (int i = t; i < 4 * ORIGD; i += 256) {
        int a = i / ORIGD, k = i - a * ORIGD;
        al[a][k] = af[(size_t)(n0 + a) * ORIGD + k];
    }
    __syncthreads();
    int c = t & 63, a = t >> 6;
    float acc = 0.f;
    #pragma unroll 4
    for (int k = 0; k < ORIGD; ++k)
        acc += al[a][k] * wl[k * AA + c];
    x[(size_t)(n0 + a) * AA + c] = acc;
}

// ---------------- y0 = x@W[0:64], y1 = x@W[64:128] ----------------
__global__ __launch_bounds__(256) void k_y01(const float* __restrict__ x,
                                             const float* __restrict__ W, // 169x128 layer base
                                             float* __restrict__ y0, float* __restrict__ y1) {
    __shared__ float wl[64 * 128];
    __shared__ float xl[16][AA];
    int t = threadIdx.x;
    int n0 = blockIdx.x * 16;
    for (int i = t; i < 16 * AA; i += 256) {
        int a = i >> 6, k = i & 63;
        xl[a][k] = x[(size_t)(n0 + a) * AA + k];
    }
    int tc = t & 31, sub = t >> 5;
    int c0 = tc * 4;
    for (int half = 0; half < 2; ++half) {
        if (half) __syncthreads();
        const float* Wh = W + (size_t)half * 64 * 128;
        for (int i = t; i < 64 * 128; i += 256) wl[i] = Wh[i];
        __syncthreads();
        float* yout = half ? y1 : y0;
        for (int ah = 0; ah < 2; ++ah) {
            int a = sub + ah * 8;
            float a0=0,a1=0,a2=0,a3=0;
            #pragma unroll 8
            for (int k = 0; k < AA; ++k) {
                float xv = xl[a][k];
                float4 w4 = *reinterpret_cast<const float4*>(&wl[k * 128 + c0]);
                a0 += xv * w4.x; a1 += xv * w4.y; a2 += xv * w4.z; a3 += xv * w4.w;
            }
            float4 r = {a0,a1,a2,a3};
            *reinterpret_cast<float4*>(&yout[(size_t)(n0 + a) * 128 + c0]) = r;
        }
    }
}

// ================= MFMA edge-GEMM passes =================
// Per block: 16 atoms -> 192 edges. GEMM: [192 x 64pad] @ [64pad x 128] in bf16.
// Al rows stride 72 (144B: 16B-aligned, bank-shift 4/row). Bl = pre-transposed Bt, flat copy.

__device__ __forceinline__ void stage_AB(int t, int n0,
                                         const unsigned short* __restrict__ nfb,
                                         const unsigned short* __restrict__ Bt,
                                         const int* __restrict__ nidx,
                                         unsigned short* Al, unsigned short* Bl, int* il) {
    const unsigned short* ng = nfb + (size_t)n0 * MM * 64;
    for (int i = t; i < 192 * 8; i += 256) {        // 16B chunks, re-stride 64 -> 72
        int m = i >> 3, c = i & 7;
        *reinterpret_cast<uint4*>(&Al[m * 72 + c * 8]) =
            *reinterpret_cast<const uint4*>(&ng[m * 64 + c * 8]);
    }
    for (int i = t; i < 128 * 9; i += 256)          // Bt already in [128][72] layout
        *reinterpret_cast<uint4*>(&Bl[i * 8]) = *reinterpret_cast<const uint4*>(&Bt[i * 8]);
    for (int i = t; i < 192; i += 256) il[i] = nidx[n0 * MM + i];
}

#define MFMA_LOOP(acc, Al, Bl, w, ln, quad)                                         \
    _Pragma("unroll")                                                               \
    for (int mt = 0; mt < 3; ++mt) {                                                \
        int mrow = ((w) * 3 + mt) * 16 + (ln);                                      \
        s16x8 a0 = *reinterpret_cast<const s16x8*>(&(Al)[mrow * 72 + (quad) * 8]);  \
        s16x8 a1 = *reinterpret_cast<const s16x8*>(&(Al)[mrow * 72 + (quad) * 8 + 32]); \
        _Pragma("unroll")                                                           \
        for (int nt = 0; nt < 8; ++nt) {                                            \
            int nrow = nt * 16 + (ln);                                              \
            s16x8 b0 = *reinterpret_cast<const s16x8*>(&(Bl)[nrow * 72 + (quad) * 8]);      \
            s16x8 b1 = *reinterpret_cast<const s16x8*>(&(Bl)[nrow * 72 + (quad) * 8 + 32]); \
            acc[mt][nt] = __builtin_amdgcn_mfma_f32_16x16x32_bf16(a0, b0, acc[mt][nt], 0, 0, 0); \
            acc[mt][nt] = __builtin_amdgcn_mfma_f32_16x16x32_bf16(a1, b1, acc[mt][nt], 0, 0, 0); \
        }                                                                           \
    }

// pass A: stats (sum, sumsq per col) of gated = y0[a] + y1[g] + nf@W2
__global__ __launch_bounds__(256, 3) void k_passA(const float* __restrict__ y0,
                                                  const float* __restrict__ y1,
                                                  const unsigned short* __restrict__ nfb,
                                                  const unsigned short* __restrict__ Bt,
                                                  const int* __restrict__ nidx,
                                                  float* __restrict__ stats) {
    __shared__ __attribute__((aligned(16))) unsigned short Al[192 * 72]; // 27648B
    __shared__ __attribute__((aligned(16))) unsigned short Bl[128 * 72]; // 18432B
    __shared__ int il[192];
    int t = threadIdx.x;
    int n0 = blockIdx.x * 16;
    stage_AB(t, n0, nfb, Bt, nidx, Al, Bl, il);
    __syncthreads();

    int w = t >> 6, lane = t & 63, ln = lane & 15, quad = lane >> 4;
    f32x4 acc[3][8];
    f32x4 z4 = {0.f, 0.f, 0.f, 0.f};
    for (int i = 0; i < 3; ++i) for (int j = 0; j < 8; ++j) acc[i][j] = z4;
    MFMA_LOOP(acc, Al, Bl, w, ln, quad);
    __syncthreads(); // all waves done with Al before aliasing as red

    float s[8] = {0,0,0,0,0,0,0,0}, q[8] = {0,0,0,0,0,0,0,0};
    #pragma unroll
    for (int mt = 0; mt < 3; ++mt) {
        #pragma unroll
        for (int reg = 0; reg < 4; ++reg) {
            int m = (w * 3 + mt) * 16 + quad * 4 + reg;
            int a = m / MM;
            const float* y0r = y0 + (size_t)(n0 + a) * 128;
            const float* y1r = y1 + (size_t)il[m] * 128;
            #pragma unroll
            for (int nt = 0; nt < 8; ++nt) {
                int n = nt * 16 + ln;
                float r = acc[mt][nt][reg] + y0r[n] + y1r[n];
                s[nt] += r; q[nt] += r * r;
            }
        }
    }
    #pragma unroll
    for (int nt = 0; nt < 8; ++nt) {
        s[nt] += __shfl_xor(s[nt], 16); s[nt] += __shfl_xor(s[nt], 32);
        q[nt] += __shfl_xor(q[nt], 16); q[nt] += __shfl_xor(q[nt], 32);
    }
    float* red = reinterpret_cast<float*>(Al); // [4 waves][8 nt][16 ln][2]
    if (quad == 0) {
        #pragma unroll
        for (int nt = 0; nt < 8; ++nt) {
            red[((w * 8 + nt) * 16 + ln) * 2 + 0] = s[nt];
            red[((w * 8 + nt) * 16 + ln) * 2 + 1] = q[nt];
        }
    }
    __syncthreads();
    {
        int c = t >> 1, j = t & 1; // c in 0..127
        float v = 0.f;
        #pragma unroll
        for (int w2 = 0; w2 < 4; ++w2)
            v += red[((w2 * 8 + (c >> 4)) * 16 + (c & 15)) * 2 + j];
        atomicAdd(&stats[j * 128 + c], v);
    }
}

// ---------------- bn1 fold ----------------
__global__ void k_sc1(const float* __restrict__ stats, const float* __restrict__ g,
                      const float* __restrict__ b, float* __restrict__ sc) {
    int c = threadIdx.x; // 128
    float cnt = (float)NEDGE;
    float mean = stats[c] / cnt;
    float var = stats[128 + c] / cnt - mean * mean;
    float inv = rsqrtf(var + EPS_BN);
    float scale = g[c] * inv;
    sc[c] = scale;
    sc[128 + c] = b[c] - mean * scale;
}

// pass B: recompute gated, BN1 + sigmoid*softplus, sum over neighbors; bn2 stats
__global__ __launch_bounds__(256, 3) void k_passB(const float* __restrict__ y0,
                                                  const float* __restrict__ y1,
                                                  const unsigned short* __restrict__ nfb,
                                                  const unsigned short* __restrict__ Bt,
                                                  const int* __restrict__ nidx,
                                                  const float* __restrict__ sc,
                                                  float* __restrict__ summed,
                                                  float* __restrict__ stats2) {
    __shared__ __attribute__((aligned(16))) unsigned short Al[192 * 72];
    __shared__ __attribute__((aligned(16))) unsigned short Bl[128 * 72];
    __shared__ int il[192];
    __shared__ float sred[512];
    int t = threadIdx.x;
    int n0 = blockIdx.x * 16;
    stage_AB(t, n0, nfb, Bt, nidx, Al, Bl, il);
    __syncthreads();

    int w = t >> 6, lane = t & 63, ln = lane & 15, quad = lane >> 4;
    f32x4 acc[3][8];
    f32x4 z4 = {0.f, 0.f, 0.f, 0.f};
    for (int i = 0; i < 3; ++i) for (int j = 0; j < 8; ++j) acc[i][j] = z4;
    MFMA_LOOP(acc, Al, Bl, w, ln, quad);
    __syncthreads(); // Al dead -> alias as P

    unsigned short* P = Al; // [192 edges][stride 66] bf16 sig*sp products
    float scF[4], shF[4], scC[4], shC[4];
    #pragma unroll
    for (int nt = 0; nt < 4; ++nt) {
        int cc = nt * 16 + ln;
        scF[nt] = sc[cc];      shF[nt] = sc[128 + cc];
        scC[nt] = sc[64 + cc]; shC[nt] = sc[192 + cc];
    }
    #pragma unroll
    for (int mt = 0; mt < 3; ++mt) {
        #pragma unroll
        for (int reg = 0; reg < 4; ++reg) {
            int m = (w * 3 + mt) * 16 + quad * 4 + reg;
            int a = m / MM;
            const float* y0r = y0 + (size_t)(n0 + a) * 128;
            const float* y1r = y1 + (size_t)il[m] * 128;
            #pragma unroll
            for (int nt = 0; nt < 4; ++nt) {
                int cc = nt * 16 + ln;
                float rf = (acc[mt][nt][reg]     + y0r[cc]      + y1r[cc])      * scF[nt] + shF[nt];
                float rc = (acc[mt][nt + 4][reg] + y0r[64 + cc] + y1r[64 + cc]) * scC[nt] + shC[nt];
                P[m * 66 + cc] = f2bu(fsigmoid(rf) * fsoftplus(rc));
            }
        }
    }
    __syncthreads();
    // reduce 12 edges per atom; thread t owns cc = t&63, atoms (t>>6)+4k
    int cc = t & 63, who = t >> 6;
    float sA = 0.f, qA = 0.f;
    #pragma unroll
    for (int k2 = 0; k2 < 4; ++k2) {
        int a = who + k2 * 4;
        float v = 0.f;
        #pragma unroll
        for (int j = 0; j < 12; ++j) v += u2f(P[(a * 12 + j) * 66 + cc]);
        summed[(size_t)(n0 + a) * AA + cc] = v;
        sA += v; qA += v * v;
    }
    sred[who * 64 + cc] = sA;
    sred[256 + who * 64 + cc] = qA;
    __syncthreads();
    if (t < 64) {
        float s4 = sred[t] + sred[64 + t] + sred[128 + t] + sred[192 + t];
        float q4 = sred[256 + t] + sred[320 + t] + sred[384 + t] + sred[448 + t];
        atomicAdd(&stats2[t], s4);
        atomicAdd(&stats2[64 + t], q4);
    }
}

// ---------------- bn2 fold ----------------
__global__ void k_sc2(const float* __restrict__ stats2, const float* __restrict__ g,
                      const float* __restrict__ b, float* __restrict__ sc2) {
    int c = threadIdx.x; // 64
    float cnt = (float)NATOM;
    float mean = stats2[c] / cnt;
    float var = stats2[64 + c] / cnt - mean * mean;
    float inv = rsqrtf(var + EPS_BN);
    float scale = g[c] * inv;
    sc2[c] = scale;
    sc2[64 + c] = b[c] - mean * scale;
}

// ---------------- x = softplus(x + bn2(summed)) ----------------
__global__ void k_update(float* __restrict__ x, const float* __restrict__ summed,
                         const float* __restrict__ sc2) {
    int i = blockIdx.x * blockDim.x + threadIdx.x;
    if (i < NATOM * AA) {
        int c = i & 63;
        float s = summed[i] * sc2[c] + sc2[64 + c];
        x[i] = fsoftplus(x[i] + s);
    }
}

// ---------------- bilinear head: q, fc1, log_softmax ----------------
__global__ __launch_bounds__(256) void k_q(const float* __restrict__ x, const int* __restrict__ cidx,
                                           const float* __restrict__ adjw, // 6*64*64
                                           const float* __restrict__ adjb, // 6
                                           const float* __restrict__ fc1w, // 36
                                           const float* __restrict__ fc1b, // 6
                                           float* __restrict__ logp) {
    __shared__ float Ao[64 * 64];
    __shared__ float cfl[16][64];
    __shared__ float qv[16][6];
    int t = threadIdx.x;
    int p0 = blockIdx.x * 16;
    int e = t & 63, who = t >> 6;
    for (int i = t; i < 16 * 64; i += 256) {
        int a = i >> 6, d = i & 63;
        cfl[a][d] = x[(size_t)cidx[p0 + a] * AA + d];
    }
    for (int o = 0; o < 6; ++o) {
        __syncthreads();
        for (int i = t; i < 4096; i += 256) Ao[i] = adjw[o * 4096 + i];
        __syncthreads();
        float bo = adjb[o];
        for (int aa = 0; aa < 4; ++aa) {
            int a = who * 4 + aa;
            float td = 0.f;
            #pragma unroll 8
            for (int d = 0; d < 64; ++d)
                td += cfl[a][d] * Ao[d * 64 + e];
            float v = td * cfl[a][e];
            for (int off = 32; off; off >>= 1) v += __shfl_down(v, off);
            if (e == 0) qv[a][o] = v + bo;
        }
    }
    __syncthreads();
    if (t < 16) {
        float q2[6];
        float mx = -1e30f;
        for (int o2 = 0; o2 < 6; ++o2) {
            float acc = fc1b[o2];
            for (int o = 0; o < 6; ++o) acc += qv[t][o] * fc1w[o * 6 + o2];
            q2[o2] = acc; mx = fmaxf(mx, acc);
        }
        float se = 0.f;
        for (int o2 = 0; o2 < 6; ++o2) se += __expf(q2[o2] - mx);
        float lse = mx + __logf(se);
        for (int o2 = 0; o2 < 6; ++o2) logp[(size_t)(p0 + t) * 6 + o2] = q2[o2] - lse;
    }
}

// ---------------- edge_prob broadcast write ----------------
__global__ void k_edge(const float* __restrict__ logp, float* __restrict__ out0) {
    int i4 = blockIdx.x * blockDim.x + threadIdx.x;
    if (i4 >= (NB * NPCC * NPCC * 6) / 4) return;
    int e = i4 * 4;
    int b = e / (NPCC * NPCC * 6);
    int rr = e - b * (NPCC * NPCC * 6);
    const float* lb = &logp[(size_t)b * NPCC * 6];
    float4 v;
    int r0 = rr % 300;       v.x = lb[r0];
    int r1 = (rr + 1) % 300; v.y = lb[r1];
    int r2 = (rr + 2) % 300; v.z = lb[r2];
    int r3 = (rr + 3) % 300; v.w = lb[r3];
    *reinterpret_cast<float4*>(&out0[e]) = v;
}

// ---------------- atom_feature = cf @ af_w + af_b ----------------
__global__ __launch_bounds__(256) void k_af(const float* __restrict__ x, const int* __restrict__ cidx,
                                            const float* __restrict__ afw,
                                            const float* __restrict__ afb,
                                            float* __restrict__ out1) {
    __shared__ float wl[AA * ORIGD];
    __shared__ float cfl[2][AA];
    int t = threadIdx.x;
    for (int i = t; i < AA * ORIGD; i += 256) wl[i] = afw[i];
    int p0 = blockIdx.x * 2;
    if (t < 128) {
        int a = t >> 6, e = t & 63;
        cfl[a][e] = x[(size_t)cidx[p0 + a] * AA + e];
    }
    __syncthreads();
    int a = t >> 7, c = t & 127;
    if (c < ORIGD) {
        float acc = afb[c];
        #pragma unroll 8
        for (int k = 0; k < AA; ++k)
            acc += cfl[a][k] * wl[k * ORIGD + c];
        out1[(size_t)(p0 + a) * ORIGD + c] = acc;
    }
}

extern "C" void kernel_launch(void* const* d_in, const int* in_sizes, int n_in,
                              void* d_out, int out_size, void* d_ws, size_t ws_size,
                              hipStream_t stream) {
    (void)in_sizes; (void)n_in; (void)out_size; (void)ws_size;
    const float* atom_fea  = (const float*)d_in[0];
    const float* nbr_fea   = (const float*)d_in[1];
    const int*   nbr_idx   = (const int*)d_in[2];
    const int*   cidx      = (const int*)d_in[3];
    const float* emb_w     = (const float*)d_in[4];
    const float* fc_full_w = (const float*)d_in[5];
    // d_in[6] fc_full_b: cancelled by batchnorm
    const float* bn1_g = (const float*)d_in[7];
    const float* bn1_b = (const float*)d_in[8];
    const float* bn2_g = (const float*)d_in[9];
    const float* bn2_b = (const float*)d_in[10];
    const float* adj_w = (const float*)d_in[11];
    const float* adj_b = (const float*)d_in[12];
    const float* fc1_w = (const float*)d_in[13];
    const float* fc1_b = (const float*)d_in[14];
    const float* af_w  = (const float*)d_in[15];
    const float* af_b  = (const float*)d_in[16];

    float* out0 = (float*)d_out;
    float* out1 = out0 + (size_t)NB * NPCC * NPCC * 6;

    float* ws = (float*)d_ws;
    float* x      = ws;
    float* y0     = x + (size_t)NATOM * AA;
    float* y1     = y0 + (size_t)NATOM * 128;
    float* summed = y1 + (size_t)NATOM * 128;
    float* logp   = summed + (size_t)NATOM * AA;
    float* stats1 = logp + (size_t)NATOM * 6;
    float* sc1    = stats1 + 256;
    float* stats2 = sc1 + 256;
    float* sc2    = stats2 + 128;
    float* endf   = sc2 + 128;
    size_t off = (((size_t)((char*)endf - (char*)d_ws)) + 255) & ~(size_t)255;
    unsigned short* nfb = (unsigned short*)((char*)d_ws + off);   // NEDGE*64 bf16 = 76.8MB
    unsigned short* Bt  = nfb + (size_t)NEDGE * 64;               // 128*72 bf16

    k_embed<<<NATOM / 4, 256, 0, stream>>>(atom_fea, emb_w, x);
    k_prepA<<<(NEDGE * 64) / 256, 256, 0, stream>>>(nbr_fea, nfb);
    for (int layer = 0; layer < 3; ++layer) {
        const float* W  = fc_full_w + (size_t)layer * 169 * 128;
        const float* W2 = W + 128 * 128;
        k_zero<<<3, 256, 0, stream>>>(stats1, 768);
        k_prepB<<<1, 256, 0, stream>>>(W2, Bt);
        k_y01<<<NATOM / 16, 256, 0, stream>>>(x, W, y0, y1);
        k_passA<<<NATOM / 16, 256, 0, stream>>>(y0, y1, nfb, Bt, nbr_idx, stats1);
        k_sc1<<<1, 128, 0, stream>>>(stats1, bn1_g + layer * 128, bn1_b + layer * 128, sc1);
        k_passB<<<NATOM / 16, 256, 0, stream>>>(y0, y1, nfb, Bt, nbr_idx, sc1, summed, stats2);
        k_sc2<<<1, 64, 0, stream>>>(stats2, bn2_g + layer * 64, bn2_b + layer * 64, sc2);
        k_update<<<(NATOM * AA + 255) / 256, 256, 0, stream>>>(x, summed, sc2);
    }
    k_q<<<NATOM / 16, 256, 0, stream>>>(x, cidx, adj_w, adj_b, fc1_w, fc1_b, logp);
    k_edge<<<((NB * NPCC * NPCC * 6) / 4 + 255) / 256, 256, 0, stream>>>(logp, out0);
    k_af<<<NATOM / 2, 256, 0, stream>>>(x, cidx, af_w, af_b, out1);
}

// Round 6
// 1367.614 us; speedup vs baseline: 1.6635x; 1.0343x over previous
//
#include <hip/hip_runtime.h>
#include <hip/hip_bf16.h>

#define AA 64
#define NBRF 41
#define ORIGD 92
#define NATOM 50000
#define MM 12
#define NB 1000
#define NPCC 50
#define NEDGE (NATOM*MM)
constexpr float EPS_BN = 1e-5f;

using bf16 = __hip_bfloat16;
typedef short s16x8 __attribute__((ext_vector_type(8)));
typedef float f32x4 __attribute__((ext_vector_type(4)));

__device__ __forceinline__ float u2f(unsigned short u) {
    union { float f; unsigned int i; } v; v.i = ((unsigned int)u) << 16; return v.f;
}
__device__ __forceinline__ unsigned short f2bu(float f) {
    bf16 h = __float2bfloat16(f);
    return *reinterpret_cast<unsigned short*>(&h);
}
__device__ __forceinline__ float fsigmoid(float x) {
    float e = __expf(-x);
    return __builtin_amdgcn_rcpf(1.f + e);
}
__device__ __forceinline__ float fsoftplus(float x) {
    return fmaxf(x, 0.f) + __logf(1.f + __expf(-fabsf(x)));
}

// ---------------- zero small stats region ----------------
__global__ void k_zero(float* p, int n) {
    int i = blockIdx.x * blockDim.x + threadIdx.x;
    if (i < n) p[i] = 0.f;
}

// ---------------- prep: W2^T -> bf16 [128 rows(n)][72 (k, padded)] ----------------
__global__ void k_prepB(const float* __restrict__ W2, unsigned short* __restrict__ Bt) {
    for (int i = threadIdx.x; i < 128 * 72; i += 256) {
        int n = i / 72, kk = i - n * 72;
        float v = (kk < NBRF) ? W2[kk * 128 + n] : 0.f;
        Bt[i] = f2bu(v);
    }
}

// ---------------- prep: adj_w -> Bq bf16 [384 rows(n=o*64+e)][72 (k=d, padded)] ----------------
__global__ void k_prepQ(const float* __restrict__ adjw, unsigned short* __restrict__ Bq) {
    int i = blockIdx.x * 256 + threadIdx.x; // 384*72 = 27648
    if (i >= 384 * 72) return;
    int n = i / 72, k = i - n * 72;
    float v = (k < 64) ? adjw[(n >> 6) * 4096 + k * 64 + (n & 63)] : 0.f;
    Bq[i] = f2bu(v);
}

// ---------------- embed: x = atom_fea @ emb_w  (N,92)@(92,64) ----------------
__global__ __launch_bounds__(256) void k_embed(const float* __restrict__ af,
                                               const float* __restrict__ w,
                                               float* __restrict__ x) {
    __shared__ float wl[ORIGD * AA];
    __shared__ float al[4][ORIGD];
    int t = threadIdx.x;
    for (int i = t; i < ORIGD * AA; i += 256) wl[i] = w[i];
    int n0 = blockIdx.x * 4;
    for (int i = t; i < 4 * ORIGD; i += 256) {
        int a = i / ORIGD, k = i - a * ORIGD;
        al[a][k] = af[(size_t)(n0 + a) * ORIGD + k];
    }
    __syncthreads();
    int c = t & 63, a = t >> 6;
    float acc = 0.f;
    #pragma unroll 4
    for (int k = 0; k < ORIGD; ++k)
        acc += al[a][k] * wl[k * AA + c];
    x[(size_t)(n0 + a) * AA + c] = acc;
}

// ---------------- y0 = x@W[0:64], y1 = x@W[64:128] ----------------
__global__ __launch_bounds__(256) void k_y01(const float* __restrict__ x,
                                             const float* __restrict__ W, // 169x128 layer base
                                             float* __restrict__ y0, float* __restrict__ y1) {
    __shared__ float wl[64 * 128];
    __shared__ float xl[16][AA];
    int t = threadIdx.x;
    int n0 = blockIdx.x * 16;
    for (int i = t; i < 16 * AA; i += 256) {
        int a = i >> 6, k = i & 63;
        xl[a][k] = x[(size_t)(n0 + a) * AA + k];
    }
    int tc = t & 31, sub = t >> 5;
    int c0 = tc * 4;
    for (int half = 0; half < 2; ++half) {
        if (half) __syncthreads();
        const float* Wh = W + (size_t)half * 64 * 128;
        for (int i = t; i < 64 * 128; i += 256) wl[i] = Wh[i];
        __syncthreads();
        float* yout = half ? y1 : y0;
        for (int ah = 0; ah < 2; ++ah) {
            int a = sub + ah * 8;
            float a0=0,a1=0,a2=0,a3=0;
            #pragma unroll 8
            for (int k = 0; k < AA; ++k) {
                float xv = xl[a][k];
                float4 w4 = *reinterpret_cast<const float4*>(&wl[k * 128 + c0]);
                a0 += xv * w4.x; a1 += xv * w4.y; a2 += xv * w4.z; a3 += xv * w4.w;
            }
            float4 r = {a0,a1,a2,a3};
            *reinterpret_cast<float4*>(&yout[(size_t)(n0 + a) * 128 + c0]) = r;
        }
    }
}

// ================= MFMA edge-GEMM pass A =================
// Per block: 16 atoms -> 192 edges. [192 x 64pad] @ [64pad x 128] bf16.
// Computes BN1 stats AND stores gated r = z + y0 + y1 as bf16 (swizzled, coalesced).

#define MFMA_LOOP(acc, Al, Bl, w, ln, quad)                                         \
    _Pragma("unroll")                                                               \
    for (int mt = 0; mt < 3; ++mt) {                                                \
        int mrow = ((w) * 3 + mt) * 16 + (ln);                                      \
        s16x8 a0 = *reinterpret_cast<const s16x8*>(&(Al)[mrow * 72 + (quad) * 8]);  \
        s16x8 a1 = *reinterpret_cast<const s16x8*>(&(Al)[mrow * 72 + (quad) * 8 + 32]); \
        _Pragma("unroll")                                                           \
        for (int nt = 0; nt < 8; ++nt) {                                            \
            int nrow = nt * 16 + (ln);                                              \
            s16x8 b0 = *reinterpret_cast<const s16x8*>(&(Bl)[nrow * 72 + (quad) * 8]);      \
            s16x8 b1 = *reinterpret_cast<const s16x8*>(&(Bl)[nrow * 72 + (quad) * 8 + 32]); \
            acc[mt][nt] = __builtin_amdgcn_mfma_f32_16x16x32_bf16(a0, b0, acc[mt][nt], 0, 0, 0); \
            acc[mt][nt] = __builtin_amdgcn_mfma_f32_16x16x32_bf16(a1, b1, acc[mt][nt], 0, 0, 0); \
        }                                                                           \
    }

__global__ __launch_bounds__(256, 3) void k_passA(const float* __restrict__ y0,
                                                  const float* __restrict__ y1,
                                                  const float* __restrict__ nf,
                                                  const unsigned short* __restrict__ Bt,
                                                  const int* __restrict__ nidx,
                                                  float* __restrict__ stats,
                                                  uint4* __restrict__ gated) {
    __shared__ __attribute__((aligned(16))) unsigned short Al[192 * 72]; // 27648B
    __shared__ __attribute__((aligned(16))) unsigned short Bl[128 * 72]; // 18432B
    __shared__ int il[192];
    int t = threadIdx.x;
    int n0 = blockIdx.x * 16;
    {
        const float* fg = nf + (size_t)n0 * MM * NBRF;
        for (int i = t; i < 192 * 72; i += 256) {
            int m = i / 72, k = i - m * 72;
            Al[i] = (k < NBRF) ? f2bu(fg[m * NBRF + k]) : (unsigned short)0;
        }
        for (int i = t; i < 128 * 9; i += 256)
            reinterpret_cast<uint4*>(Bl)[i] = reinterpret_cast<const uint4*>(Bt)[i];
        for (int i = t; i < 192; i += 256) il[i] = nidx[n0 * MM + i];
    }
    __syncthreads();

    int w = t >> 6, lane = t & 63, ln = lane & 15, quad = lane >> 4;
    f32x4 acc[3][8];
    f32x4 z4 = {0.f, 0.f, 0.f, 0.f};
    for (int i = 0; i < 3; ++i) for (int j = 0; j < 8; ++j) acc[i][j] = z4;
    MFMA_LOOP(acc, Al, Bl, w, ln, quad);
    __syncthreads(); // Al dead -> alias as red

    uint4* gblk = gated + (size_t)blockIdx.x * 3072;
    float s[8] = {0,0,0,0,0,0,0,0}, q[8] = {0,0,0,0,0,0,0,0};
    #pragma unroll
    for (int mt = 0; mt < 3; ++mt) {
        #pragma unroll
        for (int reg = 0; reg < 4; ++reg) {
            int m = (w * 3 + mt) * 16 + quad * 4 + reg;
            int a = m / MM;
            const float* y0r = y0 + (size_t)(n0 + a) * 128;
            const float* y1r = y1 + (size_t)il[m] * 128;
            float r[8];
            #pragma unroll
            for (int nt = 0; nt < 8; ++nt) {
                int n = nt * 16 + ln;
                r[nt] = acc[mt][nt][reg] + y0r[n] + y1r[n];
                s[nt] += r[nt]; q[nt] += r[nt] * r[nt];
            }
            uint4 u;
            u.x = (unsigned)f2bu(r[0]) | ((unsigned)f2bu(r[1]) << 16);
            u.y = (unsigned)f2bu(r[2]) | ((unsigned)f2bu(r[3]) << 16);
            u.z = (unsigned)f2bu(r[4]) | ((unsigned)f2bu(r[5]) << 16);
            u.w = (unsigned)f2bu(r[6]) | ((unsigned)f2bu(r[7]) << 16);
            gblk[(mt * 4 + reg) * 256 + t] = u; // coalesced per (mt,reg)
        }
    }
    #pragma unroll
    for (int nt = 0; nt < 8; ++nt) {
        s[nt] += __shfl_xor(s[nt], 16); s[nt] += __shfl_xor(s[nt], 32);
        q[nt] += __shfl_xor(q[nt], 16); q[nt] += __shfl_xor(q[nt], 32);
    }
    float* red = reinterpret_cast<float*>(Al); // [4 waves][8 nt][16 ln][2]
    if (quad == 0) {
        #pragma unroll
        for (int nt = 0; nt < 8; ++nt) {
            red[((w * 8 + nt) * 16 + ln) * 2 + 0] = s[nt];
            red[((w * 8 + nt) * 16 + ln) * 2 + 1] = q[nt];
        }
    }
    __syncthreads();
    {
        int c = t >> 1, j = t & 1; // c in 0..127
        float v = 0.f;
        #pragma unroll
        for (int w2 = 0; w2 < 4; ++w2)
            v += red[((w2 * 8 + (c >> 4)) * 16 + (c & 15)) * 2 + j];
        atomicAdd(&stats[j * 128 + c], v);
    }
}

// ---------------- bn1 fold ----------------
__global__ void k_sc1(const float* __restrict__ stats, const float* __restrict__ g,
                      const float* __restrict__ b, float* __restrict__ sc) {
    int c = threadIdx.x; // 128
    float cnt = (float)NEDGE;
    float mean = stats[c] / cnt;
    float var = stats[128 + c] / cnt - mean * mean;
    float inv = rsqrtf(var + EPS_BN);
    float scale = g[c] * inv;
    sc[c] = scale;
    sc[128 + c] = b[c] - mean * scale;
}

// ---------------- pass B (streaming): read gated, BN1+act, sum over neighbors ----------------
__global__ __launch_bounds__(256) void k_passBs(const uint4* __restrict__ gated,
                                                const float* __restrict__ sc,
                                                float* __restrict__ summed,
                                                float* __restrict__ stats2) {
    __shared__ unsigned short P[192 * 66]; // 25344B
    __shared__ float sred[512];
    int t = threadIdx.x;
    int n0 = blockIdx.x * 16;
    int w = t >> 6, lane = t & 63, ln = lane & 15, quad = lane >> 4;
    float scF[4], shF[4], scC[4], shC[4];
    #pragma unroll
    for (int nt = 0; nt < 4; ++nt) {
        int cc = nt * 16 + ln;
        scF[nt] = sc[cc];      shF[nt] = sc[128 + cc];
        scC[nt] = sc[64 + cc]; shC[nt] = sc[192 + cc];
    }
    const uint4* gblk = gated + (size_t)blockIdx.x * 3072;
    #pragma unroll
    for (int mt = 0; mt < 3; ++mt) {
        #pragma unroll
        for (int reg = 0; reg < 4; ++reg) {
            uint4 u = gblk[(mt * 4 + reg) * 256 + t];
            int m = (w * 3 + mt) * 16 + quad * 4 + reg;
            unsigned uu[4] = {u.x, u.y, u.z, u.w};
            #pragma unroll
            for (int nt = 0; nt < 4; ++nt) {
                // filter col from uu[nt>>1] halves (nt), core from uu[2+(nt>>1)]
                float rfv = u2f((unsigned short)((nt & 1) ? (uu[nt >> 1] >> 16) : (uu[nt >> 1] & 0xffff)));
                float rcv = u2f((unsigned short)((nt & 1) ? (uu[2 + (nt >> 1)] >> 16) : (uu[2 + (nt >> 1)] & 0xffff)));
                float rf = rfv * scF[nt] + shF[nt];
                float rc = rcv * scC[nt] + shC[nt];
                P[m * 66 + nt * 16 + ln] = f2bu(fsigmoid(rf) * fsoftplus(rc));
            }
        }
    }
    __syncthreads();
    int cc = t & 63, who = t >> 6;
    float sA = 0.f, qA = 0.f;
    #pragma unroll
    for (int k2 = 0; k2 < 4; ++k2) {
        int a = who + k2 * 4;
        float v = 0.f;
        #pragma unroll
        for (int j = 0; j < 12; ++j) v += u2f(P[(a * 12 + j) * 66 + cc]);
        summed[(size_t)(n0 + a) * AA + cc] = v;
        sA += v; qA += v * v;
    }
    sred[who * 64 + cc] = sA;
    sred[256 + who * 64 + cc] = qA;
    __syncthreads();
    if (t < 64) {
        float s4 = sred[t] + sred[64 + t] + sred[128 + t] + sred[192 + t];
        float q4 = sred[256 + t] + sred[320 + t] + sred[384 + t] + sred[448 + t];
        atomicAdd(&stats2[t], s4);
        atomicAdd(&stats2[64 + t], q4);
    }
}

// NOTE on passA/passBs packing: uint u.x={nt0,nt1}, u.y={nt2,nt3} (filter cols nt*16+ln),
// u.z={nt4,nt5}, u.w={nt6,nt7} (core cols 64+...). passBs mapping above matches:
// filter nt -> uu[nt>>1], core nt -> uu[2+(nt>>1)].

// ---------------- bn2 fold ----------------
__global__ void k_sc2(const float* __restrict__ stats2, const float* __restrict__ g,
                      const float* __restrict__ b, float* __restrict__ sc2) {
    int c = threadIdx.x; // 64
    float cnt = (float)NATOM;
    float mean = stats2[c] / cnt;
    float var = stats2[64 + c] / cnt - mean * mean;
    float inv = rsqrtf(var + EPS_BN);
    float scale = g[c] * inv;
    sc2[c] = scale;
    sc2[64 + c] = b[c] - mean * scale;
}

// ---------------- x = softplus(x + bn2(summed)) ----------------
__global__ void k_update(float* __restrict__ x, const float* __restrict__ summed,
                         const float* __restrict__ sc2) {
    int i = blockIdx.x * blockDim.x + threadIdx.x;
    if (i < NATOM * AA) {
        int c = i & 63;
        float s = summed[i] * sc2[c] + sc2[64 + c];
        x[i] = fsoftplus(x[i] + s);
    }
}

// ---------------- bilinear head via MFMA: T = CF @ Bq^T-layout, q, fc1, log_softmax ----------------
__global__ __launch_bounds__(256) void k_q(const float* __restrict__ x, const int* __restrict__ cidx,
                                           const unsigned short* __restrict__ Bq, // 384x72 bf16
                                           const float* __restrict__ adjb,
                                           const float* __restrict__ fc1w,
                                           const float* __restrict__ fc1b,
                                           float* __restrict__ logp) {
    __shared__ __attribute__((aligned(16))) unsigned short Aq[64 * 72];  // 9216B
    __shared__ __attribute__((aligned(16))) unsigned short Bl[384 * 72]; // 55296B
    __shared__ float qv[64][6];
    int t = threadIdx.x;
    int p0 = blockIdx.x * 64;
    for (int i = t; i < 64 * 72; i += 256) {
        int a = i / 72, k = i - a * 72;
        int ga = p0 + a;
        float v = (k < 64 && ga < NATOM) ? x[(size_t)cidx[ga < NATOM ? ga : 0] * AA + k] : 0.f;
        Aq[i] = f2bu(v);
    }
    for (int i = t; i < 3456; i += 256)
        reinterpret_cast<uint4*>(Bl)[i] = reinterpret_cast<const uint4*>(Bq)[i];
    __syncthreads();

    int w = t >> 6, lane = t & 63, ln = lane & 15, quad = lane >> 4;
    f32x4 acc[24];
    f32x4 z4 = {0.f, 0.f, 0.f, 0.f};
    #pragma unroll
    for (int i = 0; i < 24; ++i) acc[i] = z4;
    {
        int mrow = w * 16 + ln;
        s16x8 a0 = *reinterpret_cast<const s16x8*>(&Aq[mrow * 72 + quad * 8]);
        s16x8 a1 = *reinterpret_cast<const s16x8*>(&Aq[mrow * 72 + quad * 8 + 32]);
        #pragma unroll
        for (int nt = 0; nt < 24; ++nt) {
            int nrow = nt * 16 + ln;
            s16x8 b0 = *reinterpret_cast<const s16x8*>(&Bl[nrow * 72 + quad * 8]);
            s16x8 b1 = *reinterpret_cast<const s16x8*>(&Bl[nrow * 72 + quad * 8 + 32]);
            acc[nt] = __builtin_amdgcn_mfma_f32_16x16x32_bf16(a0, b0, acc[nt], 0, 0, 0);
            acc[nt] = __builtin_amdgcn_mfma_f32_16x16x32_bf16(a1, b1, acc[nt], 0, 0, 0);
        }
    }
    // epilogue: q[a][o] = sum_e T[a][o*64+e] * cf[a][e]
    float cfv[4][4];
    #pragma unroll
    for (int reg = 0; reg < 4; ++reg) {
        int ga = p0 + w * 16 + quad * 4 + reg;
        const float* xr = x + (size_t)cidx[ga < NATOM ? ga : 0] * AA;
        #pragma unroll
        for (int et = 0; et < 4; ++et)
            cfv[reg][et] = (ga < NATOM) ? xr[et * 16 + ln] : 0.f;
    }
    float bo[6];
    #pragma unroll
    for (int o = 0; o < 6; ++o) bo[o] = adjb[o];
    #pragma unroll
    for (int reg = 0; reg < 4; ++reg) {
        #pragma unroll
        for (int o = 0; o < 6; ++o) {
            float p = 0.f;
            #pragma unroll
            for (int et = 0; et < 4; ++et)
                p += acc[o * 4 + et][reg] * cfv[reg][et];
            p += __shfl_xor(p, 1); p += __shfl_xor(p, 2);
            p += __shfl_xor(p, 4); p += __shfl_xor(p, 8);
            if (ln == 0) qv[w * 16 + quad * 4 + reg][o] = p + bo[o];
        }
    }
    __syncthreads();
    if (t < 64) {
        int ga = p0 + t;
        if (ga < NATOM) {
            float q2[6];
            float mx = -1e30f;
            #pragma unroll
            for (int o2 = 0; o2 < 6; ++o2) {
                float acc2 = fc1b[o2];
                #pragma unroll
                for (int o = 0; o < 6; ++o) acc2 += qv[t][o] * fc1w[o * 6 + o2];
                q2[o2] = acc2; mx = fmaxf(mx, acc2);
            }
            float se = 0.f;
            #pragma unroll
            for (int o2 = 0; o2 < 6; ++o2) se += __expf(q2[o2] - mx);
            float lse = mx + __logf(se);
            #pragma unroll
            for (int o2 = 0; o2 < 6; ++o2) logp[(size_t)ga * 6 + o2] = q2[o2] - lse;
        }
    }
}

// ---------------- edge_prob broadcast write ----------------
__global__ void k_edge(const float* __restrict__ logp, float* __restrict__ out0) {
    int i4 = blockIdx.x * blockDim.x + threadIdx.x;
    if (i4 >= (NB * NPCC * NPCC * 6) / 4) return;
    int e = i4 * 4;
    int b = e / (NPCC * NPCC * 6);
    int rr = e - b * (NPCC * NPCC * 6);
    const float* lb = &logp[(size_t)b * NPCC * 6];
    float4 v;
    int r0 = rr % 300;       v.x = lb[r0];
    int r1 = (rr + 1) % 300; v.y = lb[r1];
    int r2 = (rr + 2) % 300; v.z = lb[r2];
    int r3 = (rr + 3) % 300; v.w = lb[r3];
    *reinterpret_cast<float4*>(&out0[e]) = v;
}

// ---------------- atom_feature = cf @ af_w + af_b ----------------
__global__ __launch_bounds__(256) void k_af(const float* __restrict__ x, const int* __restrict__ cidx,
                                            const float* __restrict__ afw,
                                            const float* __restrict__ afb,
                                            float* __restrict__ out1) {
    __shared__ float wl[AA * ORIGD];
    __shared__ float cfl[2][AA];
    int t = threadIdx.x;
    for (int i = t; i < AA * ORIGD; i += 256) wl[i] = afw[i];
    int p0 = blockIdx.x * 2;
    if (t < 128) {
        int a = t >> 6, e = t & 63;
        cfl[a][e] = x[(size_t)cidx[p0 + a] * AA + e];
    }
    __syncthreads();
    int a = t >> 7, c = t & 127;
    if (c < ORIGD) {
        float acc = afb[c];
        #pragma unroll 8
        for (int k = 0; k < AA; ++k)
            acc += cfl[a][k] * wl[k * ORIGD + c];
        out1[(size_t)(p0 + a) * ORIGD + c] = acc;
    }
}

extern "C" void kernel_launch(void* const* d_in, const int* in_sizes, int n_in,
                              void* d_out, int out_size, void* d_ws, size_t ws_size,
                              hipStream_t stream) {
    (void)in_sizes; (void)n_in; (void)out_size; (void)ws_size;
    const float* atom_fea  = (const float*)d_in[0];
    const float* nbr_fea   = (const float*)d_in[1];
    const int*   nbr_idx   = (const int*)d_in[2];
    const int*   cidx      = (const int*)d_in[3];
    const float* emb_w     = (const float*)d_in[4];
    const float* fc_full_w = (const float*)d_in[5];
    // d_in[6] fc_full_b: cancelled by batchnorm
    const float* bn1_g = (const float*)d_in[7];
    const float* bn1_b = (const float*)d_in[8];
    const float* bn2_g = (const float*)d_in[9];
    const float* bn2_b = (const float*)d_in[10];
    const float* adj_w = (const float*)d_in[11];
    const float* adj_b = (const float*)d_in[12];
    const float* fc1_w = (const float*)d_in[13];
    const float* fc1_b = (const float*)d_in[14];
    const float* af_w  = (const float*)d_in[15];
    const float* af_b  = (const float*)d_in[16];

    float* out0 = (float*)d_out;
    float* out1 = out0 + (size_t)NB * NPCC * NPCC * 6;

    float* ws = (float*)d_ws;
    float* x      = ws;
    float* y0     = x + (size_t)NATOM * AA;
    float* y1     = y0 + (size_t)NATOM * 128;
    float* summed = y1 + (size_t)NATOM * 128;
    float* logp   = summed + (size_t)NATOM * AA;
    float* stats1 = logp + (size_t)NATOM * 6;
    float* sc1    = stats1 + 256;
    float* stats2 = sc1 + 256;
    float* sc2    = stats2 + 128;
    float* endf   = sc2 + 128;
    size_t off = (((size_t)((char*)endf - (char*)d_ws)) + 255) & ~(size_t)255;
    unsigned short* Bt = (unsigned short*)((char*)d_ws + off);   // 128*72 bf16
    unsigned short* Bq = Bt + 128 * 72;                          // 384*72 bf16
    size_t goff = (off + (128 * 72 + 384 * 72) * 2 + 255) & ~(size_t)255;
    uint4* gated = (uint4*)((char*)d_ws + goff);                 // 3125*3072 uint4 = 153.6MB

    k_embed<<<NATOM / 4, 256, 0, stream>>>(atom_fea, emb_w, x);
    k_prepQ<<<108, 256, 0, stream>>>(adj_w, Bq);
    for (int layer = 0; layer < 3; ++layer) {
        const float* W  = fc_full_w + (size_t)layer * 169 * 128;
        const float* W2 = W + 128 * 128;
        k_zero<<<3, 256, 0, stream>>>(stats1, 768);
        k_prepB<<<1, 256, 0, stream>>>(W2, Bt);
        k_y01<<<NATOM / 16, 256, 0, stream>>>(x, W, y0, y1);
        k_passA<<<NATOM / 16, 256, 0, stream>>>(y0, y1, nbr_fea, Bt, nbr_idx, stats1, gated);
        k_sc1<<<1, 128, 0, stream>>>(stats1, bn1_g + layer * 128, bn1_b + layer * 128, sc1);
        k_passBs<<<NATOM / 16, 256, 0, stream>>>(gated, sc1, summed, stats2);
        k_sc2<<<1, 64, 0, stream>>>(stats2, bn2_g + layer * 64, bn2_b + layer * 64, sc2);
        k_update<<<(NATOM * AA + 255) / 256, 256, 0, stream>>>(x, summed, sc2);
    }
    k_q<<<(NATOM + 63) / 64, 256, 0, stream>>>(x, cidx, Bq, adj_b, fc1_w, fc1_b, logp);
    k_edge<<<((NB * NPCC * NPCC * 6) / 4 + 255) / 256, 256, 0, stream>>>(logp, out0);
    k_af<<<NATOM / 2, 256, 0, stream>>>(x, cidx, af_w, af_b, out1);
}